// Round 1
// baseline (15233.344 us; speedup 1.0000x reference)
//
#include <hip/hip_runtime.h>

#define UNITS 65
#define SEQ   8192
#define BATCH 50

__device__ __forceinline__ float frcp(float x){ return __builtin_amdgcn_rcpf(x); }
__device__ __forceinline__ float fsigmoid(float x){ return frcp(1.0f + __expf(-x)); }
__device__ __forceinline__ float ftanh(float x){
    float e2 = __expf(2.0f * x);
    return 1.0f - 2.0f * frcp(e2 + 1.0f);
}

// DPP helpers (VALU pipe, no LDS traffic)
template<int CTRL>
__device__ __forceinline__ float dppadd(float x){
    int t = __builtin_amdgcn_update_dpp(0, __float_as_int(x), CTRL, 0xF, 0xF, true);
    return x + __int_as_float(t);
}
template<int CTRL>
__device__ __forceinline__ float dppmov(float x){
    int t = __builtin_amdgcn_update_dpp(0, __float_as_int(x), CTRL, 0xF, 0xF, true);
    return __int_as_float(t);
}
// sum over each quad; every lane of the quad gets the full sum
__device__ __forceinline__ float red4_all(float x){
    x = dppadd<0xB1>(x);   // quad_perm [1,0,3,2]
    x = dppadd<0x4E>(x);   // quad_perm [2,3,0,1]
    return x;
}
// 16-lane row sum; row total lands in lane (16*row + 15)
__device__ __forceinline__ float red16_lane15(float x){
    x = dppadd<0x111>(x);  // row_shr:1
    x = dppadd<0x112>(x);  // row_shr:2
    x = dppadd<0x114>(x);  // row_shr:4
    x = dppadd<0x118>(x);  // row_shr:8
    return x;
}
// barrier WITHOUT vmcnt drain (LDS ordering only) — globals here are block-private
__device__ __forceinline__ void bar_lds(){
    asm volatile("s_waitcnt lgkmcnt(0)\n\ts_barrier" ::: "memory");
}
__device__ __forceinline__ float rdlane(float v, int l){
    return __int_as_float(__builtin_amdgcn_readlane(__float_as_int(v), l));
}

// v layout: k in [0,130): k<65 -> in[k], k>=65 -> h[k-65]; 4 chunks at stride 36
// (chunks of 32,32,32,34; pads zeroed once and never written)
__device__ __forceinline__ int inpos(int k){
    int q = k >> 5; if (q > 3) q = 3;
    return q * 36 + (k - (q << 5));
}
// row k of concatenated [W;U] (K=130), column c
__device__ __forceinline__ float wrow(const float* W, const float* U, int k, int c){
    return (k < 65) ? W[k * 260 + c] : U[(k - 65) * 260 + c];
}

// ---------------------------------------------------------------------------
// Layer-pipelined 3-stack LSTM.
// Pipeline step s computes, CONCURRENTLY (independent by dataflow):
//   layer0 @ t=s   : v0 = [x(s)      | h1(s-1)]
//   layer1 @ t=s-1 : v1 = [h1(s-1)   | h2(s-2)]
//   layer2 @ t=s-2 : v2 = [h2(s-2)   | h3(s-3)]  -> out row t=s-2
// Each wave owns 16 units (j = wave*16 + jl) for ALL THREE layers (weights are
// shared across layers -> one 136-VGPR weight set, 3 independent FMA streams).
// Unit 64 of layer (wave-1) is computed IN-WAVE by waves 1..3: 4 gates x 16
// lanes, red16 + readlane -> no cross-wave ebuf, so ONE barrier per step.
// 8194 steps x 1 barrier vs previous 24576 cells x 2 barriers.
// ---------------------------------------------------------------------------

#define LOADVV(vv, base) do {                                                  \
    const float* vp_ = (base) + kq * 36;                                       \
    _Pragma("unroll")                                                          \
    for (int q8_ = 0; q8_ < 8; ++q8_) {                                        \
        float4 f_ = *(const float4*)(vp_ + 4 * q8_);                           \
        vv[4*q8_+0] = f_.x; vv[4*q8_+1] = f_.y;                                \
        vv[4*q8_+2] = f_.z; vv[4*q8_+3] = f_.w;                                \
    }                                                                          \
    { float2 f2_ = *(const float2*)(vp_ + 32); vv[32] = f2_.x; vv[33] = f2_.y; } \
} while (0)

// Phase B for one layer's regular units. Writer lane (kq==3) commits state and
// performs WRITES (uses hn_).
#define LAYERB(aI, aF, aG, aO, CST, ...) do {                                  \
    float rI_ = red4_all(aI), rF_ = red4_all(aF);                              \
    float rG_ = red4_all(aG), rO_ = red4_all(aO);                              \
    float z_ = ((kq == 0) ? rI_ : (kq == 1) ? rF_ : (kq == 2) ? rG_ : rO_) + breg; \
    float sg_ = frcp(1.0f + __expf(-sk * z_));                                 \
    float g_  = fmaf(sk, sg_, dk);                                             \
    float gi_ = dppmov<0x00>(g_);                                              \
    float gf_ = dppmov<0x55>(g_);                                              \
    float gg_ = dppmov<0xAA>(g_);                                              \
    float cn_ = fmaf(gf_, CST, gi_ * gg_);                                     \
    float hn_ = g_ * ftanh(cn_);                                               \
    if (wr) { CST = cn_; __VA_ARGS__; }                                        \
} while (0)

#define STEP(L0, L1, L2) do {                                                  \
    const float* __restrict__ vbase = &vbuf[cur][0][0];                        \
    float*       __restrict__ nbase = &vbuf[cur ^ 1][0][0];                    \
    /* issue x prefetch early; consumed at step end (≈1 step in flight) */     \
    float xq1 = 0.0f, ex1 = 0.0f;                                              \
    if (L0) {                                                                  \
        const int tl_ = (s + 2 < SEQ) ? (s + 2) : (SEQ - 1);                   \
        if (wr) xq1 = xrow[(size_t)tl_ * UNITS + j];                           \
        if (wave == 1 && lane == 0) ex1 = xrow[(size_t)tl_ * UNITS + 64];      \
    }                                                                          \
    /* phase A: LDS reads (broadcast within quads) for active layers */        \
    float vv0[34], vv1[34], vv2[34];                                           \
    if (L0) LOADVV(vv0, vbase);                                                \
    if (L1) LOADVV(vv1, vbase + 144);                                          \
    if (L2) LOADVV(vv2, vbase + 288);                                          \
    /* unit-64 operands (layer ml; wave0 computes a discarded duplicate) */    \
    const float* vm_ = vbase + ml * 144;                                       \
    float4 uA_ = *(const float4*)(vm_ + p64);                                  \
    float4 uB_ = *(const float4*)(vm_ + p64 + 4);                              \
    float  uex_ = (i64 < 2) ? vm_[140 + i64] : 0.0f;                           \
    /* 12 interleaved 34-deep FMA chains (3 layers x 4 gates) */               \
    float aI0=0,aF0=0,aG0=0,aO0=0, aI1=0,aF1=0,aG1=0,aO1=0,                    \
          aI2=0,aF2=0,aG2=0,aO2=0;                                             \
    _Pragma("unroll")                                                          \
    for (int kk = 0; kk < 34; ++kk) {                                          \
        if (L0) { float s0_ = vv0[kk];                                         \
            aI0=fmaf(s0_,wI[kk],aI0); aF0=fmaf(s0_,wF[kk],aF0);                \
            aG0=fmaf(s0_,wG[kk],aG0); aO0=fmaf(s0_,wO[kk],aO0); }              \
        if (L1) { float s1_ = vv1[kk];                                         \
            aI1=fmaf(s1_,wI[kk],aI1); aF1=fmaf(s1_,wF[kk],aF1);                \
            aG1=fmaf(s1_,wG[kk],aG1); aO1=fmaf(s1_,wO[kk],aO1); }              \
        if (L2) { float s2_ = vv2[kk];                                         \
            aI2=fmaf(s2_,wI[kk],aI2); aF2=fmaf(s2_,wF[kk],aF2);                \
            aG2=fmaf(s2_,wG[kk],aG2); aO2=fmaf(s2_,wO[kk],aO2); }              \
    }                                                                          \
    /* unit-64 dot (9 MACs/lane) + in-wave row reduce */                       \
    float a64_ = uA_.x * w64[0];                                               \
    a64_ = fmaf(uA_.y, w64[1], a64_); a64_ = fmaf(uA_.z, w64[2], a64_);        \
    a64_ = fmaf(uA_.w, w64[3], a64_); a64_ = fmaf(uB_.x, w64[4], a64_);        \
    a64_ = fmaf(uB_.y, w64[5], a64_); a64_ = fmaf(uB_.z, w64[6], a64_);        \
    a64_ = fmaf(uB_.w, w64[7], a64_); a64_ = fmaf(uex_, w64x, a64_);           \
    a64_ = red16_lane15(a64_);                                                 \
    /* phase B per layer + vn writes */                                        \
    if (L0) LAYERB(aI0, aF0, aG0, aO0, c1,                                     \
                   nbase[ipH] = hn_; nbase[144 + ipI] = hn_);                  \
    if (L1) LAYERB(aI1, aF1, aG1, aO1, c2,                                     \
                   nbase[144 + ipH] = hn_; nbase[288 + ipI] = hn_);            \
    if (L2) LAYERB(aI2, aF2, aG2, aO2, c3,                                     \
                   nbase[288 + ipH] = hn_;                                     \
                   orow[(size_t)(s - 2) * UNITS + j] = hn_);                   \
    if (L0) { if (wr) { nbase[ipI] = xq0; xq0 = xq1; } }                       \
    /* unit-64 phase B: wave-uniform via readlane */                           \
    {                                                                          \
        const bool act64_ = (wave == 1) ? (bool)(L0)                           \
                          : (wave == 2) ? (bool)(L1)                           \
                          : (wave == 3) ? (bool)(L2) : false;                  \
        float zi_ = rdlane(a64_, 15) + b64i;                                   \
        float zf_ = rdlane(a64_, 31) + b64f;                                   \
        float zg_ = rdlane(a64_, 47) + b64g;                                   \
        float zo_ = rdlane(a64_, 63) + b64o;                                   \
        float gi4_ = fsigmoid(zi_), gf4_ = fsigmoid(zf_);                      \
        float gg4_ = ftanh(zg_),    go4_ = fsigmoid(zo_);                      \
        float cn64_ = fmaf(gf4_, c64, gi4_ * gg4_);                            \
        float hn64_ = go4_ * ftanh(cn64_);                                     \
        if (act64_) {                                                          \
            c64 = cn64_;                                                       \
            if (lane == 0) {                                                   \
                nbase[ml * 144 + 141] = hn64_;                                 \
                if (wave <= 2) nbase[wave * 144 + 72] = hn64_;                 \
                else orow[(size_t)(s - 2) * UNITS + 64] = hn64_;               \
            }                                                                  \
            if (wave == 1) { if (lane == 0) nbase[72] = ex0; ex0 = ex1; }      \
        }                                                                      \
    }                                                                          \
    cur ^= 1;                                                                  \
    bar_lds();                                                                 \
} while (0)

// One block per batch element. 256 threads = 4 waves (1 wave/SIMD).
// lane = jl*4 + kq: unit j = wave*16 + jl, K-chunk kq (0..3).
__global__ __launch_bounds__(256, 1)
void lstm3_kernel(const float* __restrict__ x, const float* __restrict__ W,
                  const float* __restrict__ U, const float* __restrict__ b,
                  float* __restrict__ out)
{
    const int e    = blockIdx.x;
    const int tid  = threadIdx.x;
    const int wave = tid >> 6, lane = tid & 63;
    const int kq   = lane & 3, jl = lane >> 2;
    const int j    = wave * 16 + jl;
    const bool wr  = (kq == 3);

    // [parity][layer][144]: per-layer v = [input(65) | h(65)] in chunked layout
    __shared__ __attribute__((aligned(16))) float vbuf[2][3][144];

    // ---- per-thread weights (K-chunk x 4 gates); kk>=32 for kq<3 hits v-pad zeros ----
    float wI[34], wF[34], wG[34], wO[34];
    #pragma unroll
    for (int kk = 0; kk < 34; ++kk) {
        int k = kq * 32 + kk;                 // <= 129 always
        wI[kk] = wrow(W, U, k, j);
        wF[kk] = wrow(W, U, k, 65  + j);
        wG[kk] = wrow(W, U, k, 130 + j);
        wO[kk] = wrow(W, U, k, 195 + j);
    }
    const float breg = b[kq * 65 + j];
    const float sk   = (kq == 2) ? 2.0f : 1.0f;   // g-gate: tanh(z) = 2*sigmoid(2z)-1
    const float dk   = 1.0f - sk;

    // unit-64 in-wave split: gate g64 = lane>>4, K-slice i64 = lane&15 (8 elems + rem)
    const int i64 = lane & 15, g64 = lane >> 4;
    const int p64 = (i64 >> 2) * 36 + 8 * (i64 & 3);  // inpos(8*i64), contiguous 8
    float w64[8], w64x;
    {
        const int c64 = g64 * 65 + 64;
        #pragma unroll
        for (int r = 0; r < 8; ++r) w64[r] = wrow(W, U, 8 * i64 + r, c64);
        w64x = (i64 < 2) ? wrow(W, U, 128 + i64, c64) : 0.0f;
    }
    const float b64i = b[64], b64f = b[129], b64g = b[194], b64o = b[259];
    const int ml = (wave == 0) ? 0 : wave - 1;   // unit-64 layer owned by this wave

    float c1 = 0, c2 = 0, c3 = 0, c64 = 0;       // cell states (writer lanes / uniform)

    const float* xrow = x   + (size_t)e * SEQ * UNITS;
    float*       orow = out + (size_t)e * SEQ * UNITS;
    const int ipI = inpos(j), ipH = inpos(65 + j);

    // ---- init: zero LDS (pads + h-parts must be 0), then v0.in = x(0) ----
    for (int i = tid; i < 2 * 3 * 144; i += 256) ((float*)vbuf)[i] = 0.0f;
    __syncthreads();
    if (wr)  vbuf[0][0][ipI] = xrow[j];
    if (wave == 1 && lane == 0) vbuf[0][0][72] = xrow[64];
    __syncthreads();

    // x prefetch: xq0 holds x(s+1) value at end of step s
    float xq0 = 0, ex0 = 0;
    if (wr) xq0 = xrow[UNITS + j];
    if (wave == 1 && lane == 0) ex0 = xrow[UNITS + 64];

    int cur = 0;
    int s = 0;
    STEP(1, 0, 0); ++s;                         // s=0: layer0 only
    STEP(1, 1, 0); ++s;                         // s=1: layers 0,1
    for (; s < SEQ; ++s) { STEP(1, 1, 1); }     // s=2..SEQ-1: all layers
    STEP(0, 1, 1); ++s;                         // s=SEQ: layers 1,2
    STEP(0, 0, 1);                              // s=SEQ+1: layer 2 drains
}

// Dense head, in place on d_out: out_row = row @ Wd + bd. One thread per row.
__global__ __launch_bounds__(256)
void dense_kernel(float* __restrict__ io,
                  const float* __restrict__ Wd,
                  const float* __restrict__ bd)
{
    __shared__ __attribute__((aligned(16))) float wS[65 * 68];
    __shared__ float bS[65];
    for (int i = threadIdx.x; i < 65 * 65; i += 256) {
        int r = i / 65, c = i - r * 65;
        wS[r * 68 + c] = Wd[i];
    }
    if (threadIdx.x < 65) bS[threadIdx.x] = bd[threadIdx.x];
    __syncthreads();

    const size_t row  = (size_t)blockIdx.x * 256 + threadIdx.x;
    const size_t base = row * 65;

    float r[65];
    #pragma unroll
    for (int k = 0; k < 65; ++k) r[k] = io[base + k];

    for (int ct = 0; ct < 16; ++ct) {
        const int c = ct * 4;
        float a0 = bS[c], a1 = bS[c + 1], a2 = bS[c + 2], a3 = bS[c + 3];
        #pragma unroll
        for (int k = 0; k < 65; ++k) {
            const float4 wv = *reinterpret_cast<const float4*>(&wS[k * 68 + c]);
            a0 += r[k] * wv.x;
            a1 += r[k] * wv.y;
            a2 += r[k] * wv.z;
            a3 += r[k] * wv.w;
        }
        io[base + c]     = a0;
        io[base + c + 1] = a1;
        io[base + c + 2] = a2;
        io[base + c + 3] = a3;
    }
    float a = bS[64];
    #pragma unroll
    for (int k = 0; k < 65; ++k) a += r[k] * wS[k * 68 + 64];
    io[base + 64] = a;
}

extern "C" void kernel_launch(void* const* d_in, const int* in_sizes, int n_in,
                              void* d_out, int out_size, void* d_ws, size_t ws_size,
                              hipStream_t stream)
{
    const float* x  = (const float*)d_in[0];
    const float* W  = (const float*)d_in[1];
    const float* U  = (const float*)d_in[2];
    const float* b  = (const float*)d_in[3];
    const float* Wd = (const float*)d_in[4];
    const float* bd = (const float*)d_in[5];
    float* out = (float*)d_out;

    hipLaunchKernelGGL(lstm3_kernel, dim3(BATCH), dim3(256), 0, stream, x, W, U, b, out);
    hipLaunchKernelGGL(dense_kernel, dim3(1600), dim3(256), 0, stream, out, Wd, bd);
}